// Round 2
// baseline (861.467 us; speedup 1.0000x reference)
//
#include <hip/hip_runtime.h>

#define UNITS 4096
#define DEPTH 13
#define BATCH 256

typedef __attribute__((ext_vector_type(8))) short s16x8;
typedef __attribute__((ext_vector_type(4))) short s16x4;
typedef __attribute__((ext_vector_type(4))) float f32x4;

__device__ __forceinline__ unsigned short f2bf(float f){
  unsigned u = __builtin_bit_cast(unsigned, f);
  u += 0x7FFFu + ((u >> 16) & 1u);
  return (unsigned short)(u >> 16);
}
__device__ __forceinline__ float bf2f(unsigned short u){
  return __builtin_bit_cast(float, ((unsigned)u) << 16);
}
__device__ __forceinline__ int levelof(int j){ return j ? (32 - __clz(j)) : 0; }

// ---------------- K0: prep: W2 -> bf16, W1 B-fragments, cumulative biases ----
__global__ __launch_bounds__(256) void k_prep(const float* __restrict__ W2,
    const float* __restrict__ W1,
    const float* __restrict__ b1, const float* __restrict__ b2, const float* __restrict__ b3,
    unsigned short* __restrict__ W2b, unsigned short* __restrict__ W1f,
    float* __restrict__ cb1, float* __restrict__ cb2, float* __restrict__ cb3){
  int g = blockIdx.x * 256 + threadIdx.x;
  if (g < DEPTH*64*64) W2b[g] = f2bf(W2[g]);   // [t][out][in]
  if (blockIdx.x == 208){
    // W1f[n][lane] = B-fragment for G GEMM: B[f][k], k=2m+c -> W1[m][f][c]
    int t = threadIdx.x;
    int n = t >> 6, lane = t & 63, l15 = lane & 15, kg = lane >> 4;
    int f = n*16 + l15;
    s16x8 r = {0,0,0,0,0,0,0,0};
    #pragma unroll
    for (int j = 0; j < 4; ++j){
      int m = kg*4 + j;
      if (m < DEPTH-1){
        r[2*j]   = (short)f2bf(W1[(m*64 + f)*2]);
        r[2*j+1] = (short)f2bf(W1[(m*64 + f)*2 + 1]);
      }
    }
    *(s16x8*)(W1f + (size_t)t*8) = r;
  }
  if (blockIdx.x == 209){
    int t = threadIdx.x;
    if (t < 64){
      float r = 0.f;
      cb1[t] = 0.f;
      for (int m = 1; m < DEPTH; ++m){ r += b1[(m-1)*64 + t]; cb1[m*64 + t] = r; }
      float r2 = 0.f;
      for (int m = 0; m < DEPTH; ++m){ r2 += b2[m*64 + t]; cb2[m*64 + t] = r2; }
    } else if (t < 66){
      int o = t - 64;
      float r = 0.f;
      for (int m = 0; m < DEPTH; ++m){ r += b3[m*2 + o]; cb3[m*2 + o] = r; }
    }
  }
}

// ---------------- K0b: transpose x[b][j][2] -> xT[j][b][2] --------------------
__global__ __launch_bounds__(256) void k_xpose(const float* __restrict__ x,
                                               float* __restrict__ xT){
  __shared__ float2 tile[64][65];
  int jb = (blockIdx.x & 63) * 64;
  int bb = (blockIdx.x >> 6) * 64;
  int t = threadIdx.x;
  #pragma unroll
  for (int i = 0; i < 16; ++i){
    int idx = i*256 + t;
    int jj = idx & 63, b = idx >> 6;
    tile[jj][b] = *(const float2*)(x + (((size_t)(bb + b))*UNITS + jb + jj)*2);
  }
  __syncthreads();
  #pragma unroll
  for (int i = 0; i < 16; ++i){
    int idx = i*256 + t;
    int b = idx & 63, jj = idx >> 6;
    *(float2*)(xT + (((size_t)(jb + jj))*BATCH + bb + b)*2) = tile[jj][b];
  }
}

// ---------------- K1: G[p] = sum_m W1[m] . x[p>>m]  (p = 0..2047), bf16 out ---
// One block per p. MFMA: M=256(batch) x N=64 x K=32 (k = 2m+c, zero-padded).
__global__ __launch_bounds__(256) void k_G(const float* __restrict__ xT,
    const unsigned short* __restrict__ W1f, unsigned short* __restrict__ G){
  int p = blockIdx.x;
  int lvl = levelof(p);
  int tid = threadIdx.x, wid = tid >> 6, lane = tid & 63, l15 = lane & 15, kg = lane >> 4;

  s16x8 af[4];
  #pragma unroll
  for (int m = 0; m < 4; ++m){
    int b = wid*64 + m*16 + l15;
    s16x8 r = {0,0,0,0,0,0,0,0};
    #pragma unroll
    for (int j = 0; j < 4; ++j){
      int mm = kg*4 + j;
      if (mm <= lvl){
        float2 xv = *(const float2*)(xT + ((size_t)(p >> mm)*BATCH + b)*2);
        r[2*j]   = (short)f2bf(xv.x);
        r[2*j+1] = (short)f2bf(xv.y);
      }
    }
    af[m] = r;
  }
  f32x4 acc[4][4];
  #pragma unroll
  for (int m = 0; m < 4; ++m)
    #pragma unroll
    for (int n = 0; n < 4; ++n) acc[m][n] = (f32x4){0.f,0.f,0.f,0.f};
  #pragma unroll
  for (int n = 0; n < 4; ++n){
    s16x8 bf = *(const s16x8*)(W1f + ((size_t)n*64 + lane)*8);
    #pragma unroll
    for (int m = 0; m < 4; ++m)
      acc[m][n] = __builtin_amdgcn_mfma_f32_16x16x32_bf16(af[m], bf, acc[m][n], 0, 0, 0);
  }
  #pragma unroll
  for (int m = 0; m < 4; ++m)
    #pragma unroll
    for (int n = 0; n < 4; ++n)
      #pragma unroll
      for (int i = 0; i < 4; ++i){
        int b = wid*64 + m*16 + kg*4 + i;
        int f = n*16 + l15;
        G[((size_t)p*BATCH + b)*64 + f] = f2bf(acc[m][n][i]);
      }
}

// ---------------- K2: level sweep -------------------------------------------
// D_t[v] = W2[t].h1[v] + D_{t+1}[parent];  h2 = relu(D_0 + cb2)
// E_t[v] = W3[t].h2[v] + E_{t+1}[parent];  out = E_0 + cb3
// D bf16 in fragment layout [pair][m*4+n][tid][4]; E f32 [pair][b][2].
__global__ __launch_bounds__(256) void k_sweep(
    const unsigned short* __restrict__ G, const unsigned short* __restrict__ W2b,
    const float* __restrict__ W3,
    const float* __restrict__ cb1, const float* __restrict__ cb2,
    const float* __restrict__ cb3,
    const unsigned short* __restrict__ Dprev, unsigned short* __restrict__ Dcur,
    const float* __restrict__ Eprev, float* __restrict__ Ecur,
    float* __restrict__ out, int l){
  const int v0   = (l == 0) ? 0 : (1 << (l - 1));
  const int v    = v0 + blockIdx.x;
  const int Tmax = 12 - l;
  const int pv0  = (l <= 1) ? 0 : (1 << (l - 2));
  const int Spar = 13 - l;                    // parent stored-pair stride (l>=1)

  const int tid = threadIdx.x, wid = tid >> 6, lane = tid & 63;
  const int l15 = lane & 15, kg = lane >> 4;

  // ---- h1[v] = relu(G[v>>1] + cb1[l]) as A-fragments (all zero at l==0) ----
  s16x8 af[2][4];
  if (l == 0){
    #pragma unroll
    for (int kk = 0; kk < 2; ++kk)
      #pragma unroll
      for (int m = 0; m < 4; ++m) af[kk][m] = (s16x8){0,0,0,0,0,0,0,0};
  } else {
    const unsigned short* Grow = G + (size_t)(v >> 1) * BATCH * 64;
    #pragma unroll
    for (int kk = 0; kk < 2; ++kk){
      float cbl[8];
      #pragma unroll
      for (int i = 0; i < 8; ++i) cbl[i] = cb1[l*64 + kk*32 + kg*8 + i];
      #pragma unroll
      for (int m = 0; m < 4; ++m){
        int b = wid*64 + m*16 + l15;
        s16x8 g8 = *(const s16x8*)(Grow + (size_t)b*64 + kk*32 + kg*8);
        s16x8 r;
        #pragma unroll
        for (int i = 0; i < 8; ++i){
          float gv = bf2f((unsigned short)g8[i]) + cbl[i];
          r[i] = (short)f2bf(fmaxf(gv, 0.f));
        }
        af[kk][m] = r;
      }
    }
  }

  const size_t basePD = (l >= 1) ? ((size_t)((v >> 1) - pv0) * Spar) : 0;

  for (int t = Tmax; t >= 0; --t){
    f32x4 acc[4][4];
    if (l == 0){
      #pragma unroll
      for (int m = 0; m < 4; ++m)
        #pragma unroll
        for (int n = 0; n < 4; ++n) acc[m][n] = (f32x4){0.f,0.f,0.f,0.f};
    } else {
      const unsigned short* Dp = Dprev + (basePD + t) * 16384;  // 16*256*4 u16 per pair
      #pragma unroll
      for (int m = 0; m < 4; ++m)
        #pragma unroll
        for (int n = 0; n < 4; ++n){
          s16x4 d4 = *(const s16x4*)(Dp + ((m*4 + n)*256 + tid)*4);
          f32x4 a;
          #pragma unroll
          for (int i = 0; i < 4; ++i) a[i] = bf2f((unsigned short)d4[i]);
          acc[m][n] = a;
        }
    }
    #pragma unroll
    for (int kk = 0; kk < 2; ++kk)
      #pragma unroll
      for (int n = 0; n < 4; ++n){
        s16x8 bf = *(const s16x8*)(W2b + ((size_t)t*64 + n*16 + l15)*64 + kk*32 + kg*8);
        #pragma unroll
        for (int m = 0; m < 4; ++m)
          acc[m][n] = __builtin_amdgcn_mfma_f32_16x16x32_bf16(af[kk][m], bf, acc[m][n], 0, 0, 0);
      }

    if (t > 0){
      unsigned short* Dc = Dcur + ((size_t)(v - v0) * Tmax + (t - 1)) * 16384;
      #pragma unroll
      for (int m = 0; m < 4; ++m)
        #pragma unroll
        for (int n = 0; n < 4; ++n){
          s16x4 d4;
          #pragma unroll
          for (int i = 0; i < 4; ++i) d4[i] = (short)f2bf(acc[m][n][i]);
          *(s16x4*)(Dc + ((m*4 + n)*256 + tid)*4) = d4;
        }
    } else {
      // h2 = relu(acc + cb2) in place, then E-chain + out
      float cbn[4];
      #pragma unroll
      for (int n = 0; n < 4; ++n) cbn[n] = cb2[l*64 + n*16 + l15];
      #pragma unroll
      for (int m = 0; m < 4; ++m)
        #pragma unroll
        for (int n = 0; n < 4; ++n)
          #pragma unroll
          for (int i = 0; i < 4; ++i) acc[m][n][i] = fmaxf(acc[m][n][i] + cbn[n], 0.f);

      for (int tp = 0; tp <= Tmax; ++tp){
        float w30[4], w31[4];
        #pragma unroll
        for (int n = 0; n < 4; ++n){
          w30[n] = W3[(tp*2 + 0)*64 + n*16 + l15];
          w31[n] = W3[(tp*2 + 1)*64 + n*16 + l15];
        }
        const float* Ep = Eprev + (basePD + tp) * 512;
        #pragma unroll
        for (int m = 0; m < 4; ++m)
          #pragma unroll
          for (int reg = 0; reg < 4; ++reg){
            float s0 = 0.f, s1 = 0.f;
            #pragma unroll
            for (int n = 0; n < 4; ++n){
              s0 = fmaf(w30[n], acc[m][n][reg], s0);
              s1 = fmaf(w31[n], acc[m][n][reg], s1);
            }
            #pragma unroll
            for (int d = 1; d < 16; d <<= 1){
              s0 += __shfl_xor(s0, d);
              s1 += __shfl_xor(s1, d);
            }
            if (l15 == 0){
              int b = wid*64 + m*16 + kg*4 + reg;
              if (l >= 1){ s0 += Ep[b*2]; s1 += Ep[b*2 + 1]; }
              if (tp == 0){
                float2 o; o.x = s0 + cb3[l*2]; o.y = s1 + cb3[l*2 + 1];
                *(float2*)(out + ((size_t)b*UNITS + v)*2) = o;
              } else {
                float* Ec = Ecur + ((size_t)(v - v0) * Tmax + (tp - 1)) * 512;
                Ec[b*2] = s0; Ec[b*2 + 1] = s1;
              }
            }
          }
      }
    }
  }
}

extern "C" void kernel_launch(void* const* d_in, const int* in_sizes, int n_in,
                              void* d_out, int out_size, void* d_ws, size_t ws_size,
                              hipStream_t stream){
  const float* x  = (const float*)d_in[0];
  const float* W1 = (const float*)d_in[1];
  const float* b1 = (const float*)d_in[2];
  const float* W2 = (const float*)d_in[3];
  const float* b2 = (const float*)d_in[4];
  const float* W3 = (const float*)d_in[5];
  const float* b3 = (const float*)d_in[6];
  float* out = (float*)d_out;
  char* ws = (char*)d_ws;

  unsigned short* W2b = (unsigned short*)(ws + 0);            //   106,496
  unsigned short* W1f = (unsigned short*)(ws + 106496);       //     4,096
  float* cb1 = (float*)(ws + 110592);                         //     3,328
  float* cb2 = (float*)(ws + 113920);                         //     3,328
  float* cb3 = (float*)(ws + 117248);                         //       128
  float* xT  = (float*)(ws + 117376);                         // 8,388,608
  unsigned short* G = (unsigned short*)(ws + 8505984);        // 67,108,864
  unsigned short* Dbuf[2] = {
    (unsigned short*)(ws + 75614848),                         // 33,554,432
    (unsigned short*)(ws + 109169280) };                      // 33,554,432
  float* Ebuf[2] = {
    (float*)(ws + 142723712),                                 //  2,097,152
    (float*)(ws + 144820864) };                               //  2,097,152
  // total 146,918,016 B

  hipLaunchKernelGGL(k_prep,  dim3(210),  dim3(256), 0, stream, W2, W1, b1, b2, b3, W2b, W1f, cb1, cb2, cb3);
  hipLaunchKernelGGL(k_xpose, dim3(256),  dim3(256), 0, stream, x, xT);
  hipLaunchKernelGGL(k_G,     dim3(2048), dim3(256), 0, stream, xT, W1f, G);
  for (int l = 0; l <= 12; ++l){
    int n = (l == 0) ? 1 : (1 << (l - 1));
    hipLaunchKernelGGL(k_sweep, dim3(n), dim3(256), 0, stream,
        G, W2b, W3, cb1, cb2, cb3,
        Dbuf[(l + 1) & 1], Dbuf[l & 1],
        Ebuf[(l + 1) & 1], Ebuf[l & 1],
        out, l);
  }
}

// Round 3
// 186.747 us; speedup vs baseline: 4.6130x; 4.6130x over previous
//
#include <hip/hip_runtime.h>

#define UNITS 4096
#define DEPTH 13
#define BATCH 256

typedef __attribute__((ext_vector_type(8))) short s16x8;
typedef __attribute__((ext_vector_type(4))) float f32x4;

__device__ __forceinline__ unsigned short f2bf(float f){
  unsigned u = __builtin_bit_cast(unsigned, f);
  u += 0x7FFFu + ((u >> 16) & 1u);
  return (unsigned short)(u >> 16);
}
__device__ __forceinline__ float bf2f(unsigned short u){
  return __builtin_bit_cast(float, ((unsigned)u) << 16);
}
__device__ __forceinline__ int levelof(int j){ return j ? (32 - __clz(j)) : 0; }

// ---------------- K0: prep: W2->bf16, W1 B-frags, cumulative biases, w3h20 ---
__global__ __launch_bounds__(256) void k_prep(const float* __restrict__ W2,
    const float* __restrict__ W1, const float* __restrict__ W3,
    const float* __restrict__ b1, const float* __restrict__ b2, const float* __restrict__ b3,
    unsigned short* __restrict__ W2b, unsigned short* __restrict__ W1f,
    float* __restrict__ cb1, float* __restrict__ cb2, float* __restrict__ cb3,
    float* __restrict__ w3h20){
  int g = blockIdx.x * 256 + threadIdx.x;
  if (g < DEPTH*64*64) W2b[g] = f2bf(W2[g]);   // [t][out][in]
  if (blockIdx.x == 208){
    // W1f: B-fragment for G GEMM: k = 2m+c -> W1[m][f][c]
    int t = threadIdx.x;
    int n = t >> 6, lane = t & 63, l15 = lane & 15, kg = lane >> 4;
    int f = n*16 + l15;
    s16x8 r = {0,0,0,0,0,0,0,0};
    #pragma unroll
    for (int j = 0; j < 4; ++j){
      int m = kg*4 + j;
      if (m < DEPTH-1){
        r[2*j]   = (short)f2bf(W1[(m*64 + f)*2]);
        r[2*j+1] = (short)f2bf(W1[(m*64 + f)*2 + 1]);
      }
    }
    *(s16x8*)(W1f + (size_t)t*8) = r;
  }
  if (blockIdx.x == 209){
    int t = threadIdx.x;
    if (t < 64){
      float r = 0.f;
      cb1[t] = 0.f;
      for (int m = 1; m < DEPTH; ++m){ r += b1[(m-1)*64 + t]; cb1[m*64 + t] = r; }
      float r2 = 0.f;
      for (int m = 0; m < DEPTH; ++m){ r2 += b2[m*64 + t]; cb2[m*64 + t] = r2; }
    } else if (t < 66){
      int o = t - 64;
      float r = 0.f;
      for (int m = 0; m < DEPTH; ++m){ r += b3[m*2 + o]; cb3[m*2 + o] = r; }
    } else if (t >= 128 && t < 128 + DEPTH*2){
      int q = t - 128, tt = q >> 1, o = q & 1;
      float s = 0.f;
      for (int f = 0; f < 64; ++f)
        s = fmaf(W3[(tt*2 + o)*64 + f], fmaxf(b2[f], 0.f), s);  // h2[0]=relu(b2[0][:])
      w3h20[tt*2 + o] = s;
    }
  }
}

// ---------------- K0b: transpose x[b][j][2] -> xT[j][b][2] -------------------
__global__ __launch_bounds__(256) void k_xpose(const float* __restrict__ x,
                                               float* __restrict__ xT){
  __shared__ float2 tile[64][65];
  int jb = (blockIdx.x & 63) * 64;
  int bb = (blockIdx.x >> 6) * 64;
  int t = threadIdx.x;
  #pragma unroll
  for (int i = 0; i < 16; ++i){
    int idx = i*256 + t;
    int jj = idx & 63, b = idx >> 6;
    tile[jj][b] = *(const float2*)(x + (((size_t)(bb + b))*UNITS + jb + jj)*2);
  }
  __syncthreads();
  #pragma unroll
  for (int i = 0; i < 16; ++i){
    int idx = i*256 + t;
    int b = idx & 63, jj = idx >> 6;
    *(float2*)(xT + (((size_t)(jb + jj))*BATCH + bb + b)*2) = tile[jj][b];
  }
}

// ---------------- K1: H[p] = relu(sum_m W1[m].x[p>>m] + cb1[lvl(p)+1]) -------
// Stored in MFMA-A-fragment tiled layout: idx16 = ((kk*4+kg)*256 + row)*8 + e
// (row = batch, col = kk*32+kg*8+e). One LDS transpose bounce, XOR-swizzled.
__global__ __launch_bounds__(256) void k_GH(const float* __restrict__ xT,
    const unsigned short* __restrict__ W1f, const float* __restrict__ cb1,
    unsigned short* __restrict__ H){
  __shared__ unsigned short tile[BATCH*64];  // 32 KiB
  int p = blockIdx.x;
  int lvl = levelof(p);
  int t = threadIdx.x, wid = t >> 6, lane = t & 63, l15 = lane & 15, kg = lane >> 4;

  s16x8 af[4];
  #pragma unroll
  for (int m = 0; m < 4; ++m){
    int b = wid*64 + m*16 + l15;
    s16x8 r = {0,0,0,0,0,0,0,0};
    #pragma unroll
    for (int j = 0; j < 4; ++j){
      int mm = kg*4 + j;
      if (mm <= lvl){
        float2 xv = *(const float2*)(xT + ((size_t)(p >> mm)*BATCH + b)*2);
        r[2*j]   = (short)f2bf(xv.x);
        r[2*j+1] = (short)f2bf(xv.y);
      }
    }
    af[m] = r;
  }
  f32x4 acc[4][4];
  #pragma unroll
  for (int m = 0; m < 4; ++m)
    #pragma unroll
    for (int n = 0; n < 4; ++n) acc[m][n] = (f32x4){0.f,0.f,0.f,0.f};
  #pragma unroll
  for (int n = 0; n < 4; ++n){
    s16x8 bf = *(const s16x8*)(W1f + ((size_t)n*64 + lane)*8);
    #pragma unroll
    for (int m = 0; m < 4; ++m)
      acc[m][n] = __builtin_amdgcn_mfma_f32_16x16x32_bf16(af[m], bf, acc[m][n], 0, 0, 0);
  }
  // bias + relu -> LDS (row,col) with XOR swizzle on byte addr
  int lvl1 = lvl + 1;
  float cbv[4];
  #pragma unroll
  for (int n = 0; n < 4; ++n) cbv[n] = cb1[lvl1*64 + n*16 + l15];
  #pragma unroll
  for (int m = 0; m < 4; ++m)
    #pragma unroll
    for (int n = 0; n < 4; ++n)
      #pragma unroll
      for (int i = 0; i < 4; ++i){
        int row = wid*64 + m*16 + kg*4 + i;
        int col = n*16 + l15;
        float v = fmaxf(acc[m][n][i] + cbv[n], 0.f);
        *(unsigned short*)((char*)tile + ((row*128 + col*2) ^ ((row & 7) << 4))) = f2bf(v);
      }
  __syncthreads();
  #pragma unroll
  for (int i = 0; i < 8; ++i){
    s16x8 v = *(const s16x8*)((const char*)tile + ((t*128 + i*16) ^ ((t & 7) << 4)));
    *(s16x8*)(H + (size_t)p*16384 + ((size_t)i*256 + t)*8) = v;
  }
}

// ---------------- K2: F[p] (in-reg) + fused y3 epilogue ----------------------
// F[p] = relu(cb2[lp+1] + sum_{k=0..lp} W2[k].H[p>>k]);  y3[t][p] = W3[t].F[p]
// A-frags loaded DIRECTLY from global H (tiled layout): no LDS, no barriers.
__global__ __launch_bounds__(256) void k_F(const unsigned short* __restrict__ H,
    const unsigned short* __restrict__ W2b, const float* __restrict__ cb2,
    const float* __restrict__ W3, float* __restrict__ y3){
  int p = blockIdx.x;
  int lp = levelof(p);
  int t = threadIdx.x, wid = t >> 6, lane = t & 63, l15 = lane & 15, kg = lane >> 4;

  f32x4 acc[4][4];
  #pragma unroll
  for (int m = 0; m < 4; ++m)
    #pragma unroll
    for (int n = 0; n < 4; ++n) acc[m][n] = (f32x4){0.f,0.f,0.f,0.f};

  for (int k = 0; k <= lp; ++k){
    const unsigned short* Hq = H + (size_t)(p >> k) * 16384;
    const unsigned short* Wk = W2b + (size_t)k * 4096;
    s16x8 bf[2][4];
    #pragma unroll
    for (int kk = 0; kk < 2; ++kk)
      #pragma unroll
      for (int n = 0; n < 4; ++n)
        bf[kk][n] = *(const s16x8*)(Wk + (n*16 + l15)*64 + kk*32 + kg*8);
    #pragma unroll
    for (int kk = 0; kk < 2; ++kk)
      #pragma unroll
      for (int m = 0; m < 4; ++m){
        s16x8 a = *(const s16x8*)(Hq + ((size_t)((kk*4 + kg)*256 + wid*64 + m*16 + l15))*8);
        #pragma unroll
        for (int n = 0; n < 4; ++n)
          acc[m][n] = __builtin_amdgcn_mfma_f32_16x16x32_bf16(a, bf[kk][n], acc[m][n], 0, 0, 0);
      }
  }

  // relu + bias
  float cbv[4];
  #pragma unroll
  for (int n = 0; n < 4; ++n) cbv[n] = cb2[(lp+1)*64 + n*16 + l15];
  #pragma unroll
  for (int m = 0; m < 4; ++m)
    #pragma unroll
    for (int n = 0; n < 4; ++n)
      #pragma unroll
      for (int i = 0; i < 4; ++i) acc[m][n][i] = fmaxf(acc[m][n][i] + cbv[n], 0.f);

  // y3[t][p] for t = 0..11-lp (layout y3[b][pair][2], pair = 4096-(4096>>t) + p)
  int tmax = 11 - lp;
  for (int tt = 0; tt <= tmax; ++tt){
    float w30[4], w31[4];
    #pragma unroll
    for (int n = 0; n < 4; ++n){
      w30[n] = W3[(tt*2 + 0)*64 + n*16 + l15];
      w31[n] = W3[(tt*2 + 1)*64 + n*16 + l15];
    }
    int off = 4096 - (4096 >> tt);
    #pragma unroll
    for (int m = 0; m < 4; ++m)
      #pragma unroll
      for (int reg = 0; reg < 4; ++reg){
        float s0 = 0.f, s1 = 0.f;
        #pragma unroll
        for (int n = 0; n < 4; ++n){
          s0 = fmaf(w30[n], acc[m][n][reg], s0);
          s1 = fmaf(w31[n], acc[m][n][reg], s1);
        }
        #pragma unroll
        for (int d = 1; d < 16; d <<= 1){
          s0 += __shfl_xor(s0, d);
          s1 += __shfl_xor(s1, d);
        }
        if (l15 == 0){
          int b = wid*64 + m*16 + kg*4 + reg;
          float2 v; v.x = s0; v.y = s1;
          *(float2*)(y3 + ((size_t)b*4095 + off + p)*2) = v;
        }
      }
  }
}

// ---------------- K3: out[b][2p(+1)] = L[b][p]; j=0 special ------------------
__global__ __launch_bounds__(256) void k_scatter(const float* __restrict__ y3,
    const float* __restrict__ cb3, const float* __restrict__ w3h20,
    float* __restrict__ out){
  int bid = blockIdx.x;                 // 2048 = 256 b x 8 chunks
  int b = bid >> 3;
  int p = (bid & 7)*256 + threadIdx.x;
  int lp = levelof(p);
  const float* yb = y3 + (size_t)b*4095*2;
  float s0 = cb3[(lp+1)*2]     + w3h20[(lp+1)*2];
  float s1 = cb3[(lp+1)*2 + 1] + w3h20[(lp+1)*2 + 1];
  for (int k = 0; k <= lp; ++k){
    int pi = (4096 - (4096 >> k)) + (p >> k);
    s0 += yb[pi*2];
    s1 += yb[pi*2 + 1];
  }
  float4 o;
  if (p == 0){
    o.x = cb3[0] + w3h20[0];           // j=0 (special)
    o.y = cb3[1] + w3h20[1];
    o.z = s0; o.w = s1;                // j=1 = L[0]
  } else {
    o.x = s0; o.y = s1; o.z = s0; o.w = s1;   // j=2p, 2p+1
  }
  *(float4*)(out + (size_t)b*8192 + (size_t)p*4) = o;
}

extern "C" void kernel_launch(void* const* d_in, const int* in_sizes, int n_in,
                              void* d_out, int out_size, void* d_ws, size_t ws_size,
                              hipStream_t stream){
  const float* x  = (const float*)d_in[0];
  const float* W1 = (const float*)d_in[1];
  const float* b1 = (const float*)d_in[2];
  const float* W2 = (const float*)d_in[3];
  const float* b2 = (const float*)d_in[4];
  const float* W3 = (const float*)d_in[5];
  const float* b3 = (const float*)d_in[6];
  float* out = (float*)d_out;
  char* ws = (char*)d_ws;

  unsigned short* W2b   = (unsigned short*)(ws + 0);          //   106,496
  unsigned short* W1f   = (unsigned short*)(ws + 106496);     //     4,096
  float* cb1   = (float*)(ws + 110592);                       //     3,328
  float* cb2   = (float*)(ws + 113920);                       //     3,328
  float* cb3   = (float*)(ws + 117248);                       //       128
  float* w3h20 = (float*)(ws + 117376);                       //       128
  float* xT    = (float*)(ws + 117504);                       // 8,388,608
  unsigned short* H = (unsigned short*)(ws + 8506112);        // 67,108,864
  float* y3    = (float*)(ws + 75614976);                     // 8,386,560
  // total 84,001,536 B

  hipLaunchKernelGGL(k_prep,    dim3(210),  dim3(256), 0, stream, W2, W1, W3, b1, b2, b3, W2b, W1f, cb1, cb2, cb3, w3h20);
  hipLaunchKernelGGL(k_xpose,   dim3(256),  dim3(256), 0, stream, x, xT);
  hipLaunchKernelGGL(k_GH,      dim3(2048), dim3(256), 0, stream, xT, W1f, cb1, H);
  hipLaunchKernelGGL(k_F,       dim3(2048), dim3(256), 0, stream, H, W2b, cb2, W3, y3);
  hipLaunchKernelGGL(k_scatter, dim3(2048), dim3(256), 0, stream, y3, cb3, w3h20, out);
}